// Round 1
// baseline (1674.085 us; speedup 1.0000x reference)
//
#include <hip/hip_runtime.h>
#include <math.h>

// ---------------------------------------------------------------------------
// Dense: out[M,128] = A[M,K] @ W[K,128] (+ bias). W staged in LDS.
// block = 256 threads; each block does 64 rows; micro-tile 8 rows x 4 cols.
// ---------------------------------------------------------------------------
template<int K, bool HAS_BIAS>
__global__ __launch_bounds__(256) void dense_k(
    const float* __restrict__ A, const float* __restrict__ W,
    const float* __restrict__ bias, float* __restrict__ out, int M)
{
    __shared__ float Wl[K * 128];
    const int t = threadIdx.x;
    for (int idx = t * 4; idx < K * 128; idx += 1024)
        *(float4*)&Wl[idx] = *(const float4*)&W[idx];
    __syncthreads();

    const int tx = t & 31, ty = t >> 5;
    const int c0 = tx * 4;
    const long row0 = (long)blockIdx.x * 64 + (long)ty * 8;

    const float* Ap[8];
#pragma unroll
    for (int i = 0; i < 8; i++) {
        long r = row0 + i; if (r > (long)M - 1) r = (long)M - 1;
        Ap[i] = A + r * K;
    }
    float4 acc[8];
#pragma unroll
    for (int i = 0; i < 8; i++) acc[i] = make_float4(0.f, 0.f, 0.f, 0.f);

    for (int k = 0; k < K; k += 4) {
        const float4 w0 = *(const float4*)&Wl[(k + 0) * 128 + c0];
        const float4 w1 = *(const float4*)&Wl[(k + 1) * 128 + c0];
        const float4 w2 = *(const float4*)&Wl[(k + 2) * 128 + c0];
        const float4 w3 = *(const float4*)&Wl[(k + 3) * 128 + c0];
#pragma unroll
        for (int i = 0; i < 8; i++) {
            const float4 a = *(const float4*)(Ap[i] + k);
            acc[i].x += a.x * w0.x + a.y * w1.x + a.z * w2.x + a.w * w3.x;
            acc[i].y += a.x * w0.y + a.y * w1.y + a.z * w2.y + a.w * w3.y;
            acc[i].z += a.x * w0.z + a.y * w1.z + a.z * w2.z + a.w * w3.z;
            acc[i].w += a.x * w0.w + a.y * w1.w + a.z * w2.w + a.w * w3.w;
        }
    }
    float4 bv = make_float4(0.f, 0.f, 0.f, 0.f);
    if (HAS_BIAS) bv = *(const float4*)&bias[c0];
#pragma unroll
    for (int i = 0; i < 8; i++) {
        long r = row0 + i;
        if (r < M) {
            float4 o;
            o.x = acc[i].x + bv.x; o.y = acc[i].y + bv.y;
            o.z = acc[i].z + bv.z; o.w = acc[i].w + bv.w;
            *(float4*)&out[r * 128 + c0] = o;
        }
    }
}

// ---------------------------------------------------------------------------
// Degree count (real edges only; self-loop added analytically later)
// ---------------------------------------------------------------------------
__global__ void count_edges_k(const int* __restrict__ dst, int* __restrict__ cnt, int E)
{
    int e = blockIdx.x * 256 + threadIdx.x;
    if (e < E) atomicAdd(&cnt[dst[e]], 1);
}

__global__ void dinv_k(const int* __restrict__ cnt, float* __restrict__ dinv, int N)
{
    int i = blockIdx.x * 256 + threadIdx.x;
    if (i < N) dinv[i] = rsqrtf((float)cnt[i] + 1.0f);   // +1 = self loop
}

// ---------------------------------------------------------------------------
// 3-kernel exclusive prefix scan over cnt -> offs
// ---------------------------------------------------------------------------
__global__ void scan_block_k(const int* __restrict__ cnt, int* __restrict__ offs,
                             int* __restrict__ bsums, int N)
{
    __shared__ int tmp[256];
    int i = blockIdx.x * 256 + threadIdx.x;
    int v = (i < N) ? cnt[i] : 0;
    tmp[threadIdx.x] = v;
    __syncthreads();
    for (int off = 1; off < 256; off <<= 1) {
        int add = (threadIdx.x >= off) ? tmp[threadIdx.x - off] : 0;
        __syncthreads();
        tmp[threadIdx.x] += add;
        __syncthreads();
    }
    if (i < N) offs[i] = tmp[threadIdx.x] - v;           // exclusive within block
    if (threadIdx.x == 255) bsums[blockIdx.x] = tmp[255];
}

__global__ void scan_tops_k(int* __restrict__ bsums, int nb)
{
    __shared__ int tmp[512];
    int t = threadIdx.x;
    int v = (t < nb) ? bsums[t] : 0;
    tmp[t] = v;
    __syncthreads();
    for (int off = 1; off < 512; off <<= 1) {
        int add = (t >= off) ? tmp[t - off] : 0;
        __syncthreads();
        tmp[t] += add;
        __syncthreads();
    }
    if (t < nb) bsums[t] = tmp[t] - v;                   // exclusive over blocks
}

__global__ void scan_add_k(int* __restrict__ offs, const int* __restrict__ bsums,
                           int N, int E)
{
    int i = blockIdx.x * 256 + threadIdx.x;
    if (i < N) offs[i] += bsums[blockIdx.x];
    if (i == 0) offs[N] = E;
}

// ---------------------------------------------------------------------------
// CSR fill: csr_src/csr_norm grouped by dst
// ---------------------------------------------------------------------------
__global__ void fill_csr_k(const int* __restrict__ src, const int* __restrict__ dst,
                           const int* __restrict__ offs, int* __restrict__ fillc,
                           const float* __restrict__ dinv,
                           int* __restrict__ csr_src, float* __restrict__ csr_norm, int E)
{
    int e = blockIdx.x * 256 + threadIdx.x;
    if (e >= E) return;
    int s = src[e], d = dst[e];
    int slot = offs[d] + atomicAdd(&fillc[d], 1);
    csr_src[slot] = s;
    csr_norm[slot] = dinv[s] * dinv[d];
}

// ---------------------------------------------------------------------------
// Aggregation: one wave per node, lane handles 2 features (float2).
// h_out[i] = tanh( sum_{e: dst=i} hw[src_e]*norm_e + hw[i]*dinv[i]^2 + b )
// ---------------------------------------------------------------------------
__global__ __launch_bounds__(256) void aggregate_k(
    const float* __restrict__ hw, const int* __restrict__ offs,
    const int* __restrict__ csr_src, const float* __restrict__ csr_norm,
    const float* __restrict__ dinv, const float* __restrict__ bconv,
    float* __restrict__ hout, int N)
{
    const int wid = threadIdx.x >> 6;
    const int lane = threadIdx.x & 63;
    const long node = (long)blockIdx.x * 4 + wid;
    if (node >= N) return;
    const int f = lane * 2;

    const float di = dinv[node];
    float2 acc = *(const float2*)&hw[node * 128 + f];
    acc.x *= di * di;
    acc.y *= di * di;

    const int beg = offs[node], end = offs[node + 1];
    for (int k = beg; k < end; k++) {
        const int s = csr_src[k];
        const float w = csr_norm[k];
        const float2 v = *(const float2*)&hw[(long)s * 128 + f];
        acc.x += v.x * w;
        acc.y += v.y * w;
    }
    const float2 b = *(const float2*)&bconv[f];
    float2 o;
    o.x = tanhf(acc.x + b.x);
    o.y = tanhf(acc.y + b.y);
    *(float2*)&hout[node * 128 + f] = o;
}

// ---------------------------------------------------------------------------
// Graph ranges from sorted batch
// ---------------------------------------------------------------------------
__global__ void graph_bounds_k(const int* __restrict__ batch, int* __restrict__ goffs,
                               int N, int G)
{
    int i = blockIdx.x * 256 + threadIdx.x;
    if (i >= N) return;
    int b = batch[i];
    int prev = (i == 0) ? -1 : batch[i - 1];
    for (int g = prev + 1; g <= b; g++) goffs[g] = i;
    if (i == N - 1)
        for (int g = b + 1; g <= G; g++) goffs[g] = N;
}

// ---------------------------------------------------------------------------
// Pool: one block per graph, thread = feature. gout[g] = [sum | max | mean]
// ---------------------------------------------------------------------------
__global__ __launch_bounds__(128) void pool_k(const float* __restrict__ h,
                                              const int* __restrict__ goffs,
                                              float* __restrict__ gout, int N)
{
    const int g = blockIdx.x, f = threadIdx.x;
    const int beg = goffs[g], end = goffs[g + 1];
    float s = 0.f, m = -INFINITY;
    for (int i = beg; i < end; i++) {
        float v = h[(long)i * 128 + f];
        s += v;
        m = fmaxf(m, v);
    }
    const float cntf = (float)(end - beg);
    const float mean = s / fmaxf(cntf, 1.0f);
    if (end <= beg) m = 0.0f;          // isfinite() guard in reference
    gout[g * 384 + f]       = s;
    gout[g * 384 + 128 + f] = m;
    gout[g * 384 + 256 + f] = mean;
}

// ---------------------------------------------------------------------------
// MLP head: one block per graph
// ---------------------------------------------------------------------------
__global__ __launch_bounds__(192) void mlp_k(const float* __restrict__ gbuf,
                                             const float* __restrict__ W1,
                                             const float* __restrict__ b1,
                                             const float* __restrict__ W2,
                                             const float* __restrict__ b2,
                                             float* __restrict__ out)
{
    __shared__ float gr[384];
    __shared__ float g1[192];
    const int g = blockIdx.x, t = threadIdx.x;
    for (int i = t; i < 384; i += 192) gr[i] = gbuf[g * 384 + i];
    __syncthreads();
    float acc = b1[t];
    for (int k = 0; k < 384; k++) acc += gr[k] * W1[k * 192 + t];
    acc = acc > 0.f ? acc : 0.01f * acc;
    g1[t] = acc;
    __syncthreads();
    if (t < 10) {
        float a = b2[t];
        for (int k = 0; k < 192; k++) a += g1[k] * W2[k * 10 + t];
        a = a > 0.f ? a : 0.01f * a;
        out[g * 10 + t] = a;
    }
}

// ---------------------------------------------------------------------------
extern "C" void kernel_launch(void* const* d_in, const int* in_sizes, int n_in,
                              void* d_out, int out_size, void* d_ws, size_t ws_size,
                              hipStream_t stream)
{
    const float* x      = (const float*)d_in[0];
    const int*   ei     = (const int*)d_in[1];
    const int*   batch  = (const int*)d_in[2];
    const float* W_emb  = (const float*)d_in[3];
    const float* b_emb  = (const float*)d_in[4];
    const float* W_conv = (const float*)d_in[5];
    const float* b_conv = (const float*)d_in[6];
    const float* W1     = (const float*)d_in[7];
    const float* b1     = (const float*)d_in[8];
    const float* W2     = (const float*)d_in[9];
    const float* b2     = (const float*)d_in[10];
    float* out = (float*)d_out;

    const int N  = in_sizes[2];          // 100000
    const int E  = in_sizes[1] / 2;      // 1600000
    const int G  = 128;
    const int NL = 5;
    const int HID = 128;
    const int DIN = 64;

    const int* e_src = ei;
    const int* e_dst = ei + E;

    // workspace carve-up
    char* ws = (char*)d_ws;
    size_t off = 0;
    auto alloc = [&](size_t bytes) -> void* {
        void* p = ws + off;
        off += (bytes + 255) & ~(size_t)255;
        return p;
    };
    float* hbuf     = (float*)alloc((size_t)N * HID * 4);
    float* hwbuf    = (float*)alloc((size_t)N * HID * 4);
    float* dinv     = (float*)alloc((size_t)N * 4);
    int*   cnt      = (int*)  alloc((size_t)N * 4);
    int*   offs     = (int*)  alloc((size_t)(N + 1) * 4);
    int*   bsums    = (int*)  alloc(512 * 4);
    int*   csr_src  = (int*)  alloc((size_t)E * 4);
    float* csr_norm = (float*)alloc((size_t)E * 4);
    int*   goffs    = (int*)  alloc((size_t)(G + 1) * 4);
    float* gbuf     = (float*)alloc((size_t)G * 384 * 4);

    const int nb_nodes = (N + 255) / 256;
    const int nb_edges = (E + 255) / 256;

    // 1) degree + dinv
    hipMemsetAsync(cnt, 0, (size_t)N * 4, stream);
    count_edges_k<<<nb_edges, 256, 0, stream>>>(e_dst, cnt, E);
    dinv_k<<<nb_nodes, 256, 0, stream>>>(cnt, dinv, N);

    // 2) CSR offsets (exclusive scan of cnt)
    scan_block_k<<<nb_nodes, 256, 0, stream>>>(cnt, offs, bsums, N);
    scan_tops_k<<<1, 512, 0, stream>>>(bsums, nb_nodes);
    scan_add_k<<<nb_nodes, 256, 0, stream>>>(offs, bsums, N, E);

    // 3) CSR fill
    hipMemsetAsync(cnt, 0, (size_t)N * 4, stream);
    fill_csr_k<<<nb_edges, 256, 0, stream>>>(e_src, e_dst, offs, cnt, dinv,
                                             csr_src, csr_norm, E);

    // 4) input embedding: h = x @ W_emb + b_emb
    dense_k<64, true><<<(N + 63) / 64, 256, 0, stream>>>(x, W_emb, b_emb, hbuf, N);

    // 5) GCN layers
    for (int l = 0; l < NL; l++) {
        dense_k<128, false><<<(N + 63) / 64, 256, 0, stream>>>(
            hbuf, W_conv + (size_t)l * HID * HID, nullptr, hwbuf, N);
        aggregate_k<<<(N + 3) / 4, 256, 0, stream>>>(
            hwbuf, offs, csr_src, csr_norm, dinv, b_conv + (size_t)l * HID, hbuf, N);
    }

    // 6) pooling
    graph_bounds_k<<<nb_nodes, 256, 0, stream>>>(batch, goffs, N, G);
    pool_k<<<G, 128, 0, stream>>>(hbuf, goffs, gbuf, N);

    // 7) MLP head
    mlp_k<<<G, 192, 0, stream>>>(gbuf, W1, b1, W2, b2, out);
}

// Round 2
// 1506.782 us; speedup vs baseline: 1.1110x; 1.1110x over previous
//
#include <hip/hip_runtime.h>
#include <math.h>

// ---------------------------------------------------------------------------
// Dense: out[M,128] = A[M,K] @ W[K,128] (+ bias). W staged in LDS.
// block = 256 threads; each block does 64 rows; micro-tile 8 rows x 4 cols.
// ---------------------------------------------------------------------------
template<int K, bool HAS_BIAS>
__global__ __launch_bounds__(256) void dense_k(
    const float* __restrict__ A, const float* __restrict__ W,
    const float* __restrict__ bias, float* __restrict__ out, int M)
{
    __shared__ float Wl[K * 128];
    const int t = threadIdx.x;
    for (int idx = t * 4; idx < K * 128; idx += 1024)
        *(float4*)&Wl[idx] = *(const float4*)&W[idx];
    __syncthreads();

    const int tx = t & 31, ty = t >> 5;
    const int c0 = tx * 4;
    const long row0 = (long)blockIdx.x * 64 + (long)ty * 8;

    const float* Ap[8];
#pragma unroll
    for (int i = 0; i < 8; i++) {
        long r = row0 + i; if (r > (long)M - 1) r = (long)M - 1;
        Ap[i] = A + r * K;
    }
    float4 acc[8];
#pragma unroll
    for (int i = 0; i < 8; i++) acc[i] = make_float4(0.f, 0.f, 0.f, 0.f);

    for (int k = 0; k < K; k += 4) {
        const float4 w0 = *(const float4*)&Wl[(k + 0) * 128 + c0];
        const float4 w1 = *(const float4*)&Wl[(k + 1) * 128 + c0];
        const float4 w2 = *(const float4*)&Wl[(k + 2) * 128 + c0];
        const float4 w3 = *(const float4*)&Wl[(k + 3) * 128 + c0];
#pragma unroll
        for (int i = 0; i < 8; i++) {
            const float4 a = *(const float4*)(Ap[i] + k);
            acc[i].x += a.x * w0.x + a.y * w1.x + a.z * w2.x + a.w * w3.x;
            acc[i].y += a.x * w0.y + a.y * w1.y + a.z * w2.y + a.w * w3.y;
            acc[i].z += a.x * w0.z + a.y * w1.z + a.z * w2.z + a.w * w3.z;
            acc[i].w += a.x * w0.w + a.y * w1.w + a.z * w2.w + a.w * w3.w;
        }
    }
    float4 bv = make_float4(0.f, 0.f, 0.f, 0.f);
    if (HAS_BIAS) bv = *(const float4*)&bias[c0];
#pragma unroll
    for (int i = 0; i < 8; i++) {
        long r = row0 + i;
        if (r < M) {
            float4 o;
            o.x = acc[i].x + bv.x; o.y = acc[i].y + bv.y;
            o.z = acc[i].z + bv.z; o.w = acc[i].w + bv.w;
            *(float4*)&out[r * 128 + c0] = o;
        }
    }
}

// ---------------------------------------------------------------------------
// Degree count (real edges only; self-loop added analytically later)
// ---------------------------------------------------------------------------
__global__ void count_edges_k(const int* __restrict__ dst, int* __restrict__ cnt, int E)
{
    int e = blockIdx.x * 256 + threadIdx.x;
    if (e < E) atomicAdd(&cnt[dst[e]], 1);
}

__global__ void dinv_k(const int* __restrict__ cnt, float* __restrict__ dinv, int N)
{
    int i = blockIdx.x * 256 + threadIdx.x;
    if (i < N) dinv[i] = rsqrtf((float)cnt[i] + 1.0f);   // +1 = self loop
}

// ---------------------------------------------------------------------------
// 3-kernel exclusive prefix scan over cnt -> offs
// ---------------------------------------------------------------------------
__global__ void scan_block_k(const int* __restrict__ cnt, int* __restrict__ offs,
                             int* __restrict__ bsums, int N)
{
    __shared__ int tmp[256];
    int i = blockIdx.x * 256 + threadIdx.x;
    int v = (i < N) ? cnt[i] : 0;
    tmp[threadIdx.x] = v;
    __syncthreads();
    for (int off = 1; off < 256; off <<= 1) {
        int add = (threadIdx.x >= off) ? tmp[threadIdx.x - off] : 0;
        __syncthreads();
        tmp[threadIdx.x] += add;
        __syncthreads();
    }
    if (i < N) offs[i] = tmp[threadIdx.x] - v;           // exclusive within block
    if (threadIdx.x == 255) bsums[blockIdx.x] = tmp[255];
}

__global__ void scan_tops_k(int* __restrict__ bsums, int nb)
{
    __shared__ int tmp[512];
    int t = threadIdx.x;
    int v = (t < nb) ? bsums[t] : 0;
    tmp[t] = v;
    __syncthreads();
    for (int off = 1; off < 512; off <<= 1) {
        int add = (t >= off) ? tmp[t - off] : 0;
        __syncthreads();
        tmp[t] += add;
        __syncthreads();
    }
    if (t < nb) bsums[t] = tmp[t] - v;                   // exclusive over blocks
}

__global__ void scan_add_k(int* __restrict__ offs, const int* __restrict__ bsums,
                           int N, int E)
{
    int i = blockIdx.x * 256 + threadIdx.x;
    if (i < N) offs[i] += bsums[blockIdx.x];
    if (i == 0) offs[N] = E;
}

// ---------------------------------------------------------------------------
// CSR fill: csr_src/csr_norm grouped by dst
// ---------------------------------------------------------------------------
__global__ void fill_csr_k(const int* __restrict__ src, const int* __restrict__ dst,
                           const int* __restrict__ offs, int* __restrict__ fillc,
                           const float* __restrict__ dinv,
                           int* __restrict__ csr_src, float* __restrict__ csr_norm, int E)
{
    int e = blockIdx.x * 256 + threadIdx.x;
    if (e >= E) return;
    int s = src[e], d = dst[e];
    int slot = offs[d] + atomicAdd(&fillc[d], 1);
    csr_src[slot] = s;
    csr_norm[slot] = dinv[s] * dinv[d];
}

// ---------------------------------------------------------------------------
// Aggregation: one wave per node, lane handles 2 features (float2).
// ---------------------------------------------------------------------------
__global__ __launch_bounds__(256) void aggregate_k(
    const float* __restrict__ hw, const int* __restrict__ offs,
    const int* __restrict__ csr_src, const float* __restrict__ csr_norm,
    const float* __restrict__ dinv, const float* __restrict__ bconv,
    float* __restrict__ hout, int N)
{
    const int wid = threadIdx.x >> 6;
    const int lane = threadIdx.x & 63;
    const long node = (long)blockIdx.x * 4 + wid;
    if (node >= N) return;
    const int f = lane * 2;

    const float di = dinv[node];
    float2 acc = *(const float2*)&hw[node * 128 + f];
    acc.x *= di * di;
    acc.y *= di * di;

    const int beg = offs[node], end = offs[node + 1];
    for (int k = beg; k < end; k++) {
        const int s = csr_src[k];
        const float w = csr_norm[k];
        const float2 v = *(const float2*)&hw[(long)s * 128 + f];
        acc.x += v.x * w;
        acc.y += v.y * w;
    }
    const float2 b = *(const float2*)&bconv[f];
    float2 o;
    o.x = tanhf(acc.x + b.x);
    o.y = tanhf(acc.y + b.y);
    *(float2*)&hout[node * 128 + f] = o;
}

// ---------------------------------------------------------------------------
// Graph ranges from sorted batch
// ---------------------------------------------------------------------------
__global__ void graph_bounds_k(const int* __restrict__ batch, int* __restrict__ goffs,
                               int N, int G)
{
    int i = blockIdx.x * 256 + threadIdx.x;
    if (i >= N) return;
    int b = batch[i];
    int prev = (i == 0) ? -1 : batch[i - 1];
    for (int g = prev + 1; g <= b; g++) goffs[g] = i;
    if (i == N - 1)
        for (int g = b + 1; g <= G; g++) goffs[g] = N;
}

// ---------------------------------------------------------------------------
// Pool stage 1: parallel partial reduction over node chunks.
// Order-preserving uint encoding for float atomicMax.
// ---------------------------------------------------------------------------
__device__ __forceinline__ unsigned enc_f32(float x)
{
    unsigned u = __float_as_uint(x);
    return (u & 0x80000000u) ? ~u : (u | 0x80000000u);
}
__device__ __forceinline__ float dec_f32(unsigned u)
{
    return (u & 0x80000000u) ? __uint_as_float(u ^ 0x80000000u)
                             : __uint_as_float(~u);
}

#define POOL_CHUNK 32

__global__ __launch_bounds__(128) void pool_partial_k(
    const float* __restrict__ h, const int* __restrict__ batch,
    float* __restrict__ sums, unsigned* __restrict__ maxu, int N)
{
    const int t = threadIdx.x;
    const int lane = t & 31;          // feature group: 4 floats
    const int sub = t >> 5;           // row offset within 4-row sweep
    const int f4 = lane * 4;
    const int i0 = blockIdx.x * POOL_CHUNK;
    const int i1 = min(i0 + POOL_CHUNK, N);

    int cur = -1;
    float4 s = make_float4(0.f, 0.f, 0.f, 0.f);
    float4 m = make_float4(-INFINITY, -INFINITY, -INFINITY, -INFINITY);

#pragma unroll 4
    for (int i = i0 + sub; i < i1; i += 4) {
        const int b = batch[i];
        const float4 v = *(const float4*)&h[(long)i * 128 + f4];
        if (b != cur) {
            if (cur >= 0) {
                atomicAdd(&sums[cur * 128 + f4 + 0], s.x);
                atomicAdd(&sums[cur * 128 + f4 + 1], s.y);
                atomicAdd(&sums[cur * 128 + f4 + 2], s.z);
                atomicAdd(&sums[cur * 128 + f4 + 3], s.w);
                atomicMax(&maxu[cur * 128 + f4 + 0], enc_f32(m.x));
                atomicMax(&maxu[cur * 128 + f4 + 1], enc_f32(m.y));
                atomicMax(&maxu[cur * 128 + f4 + 2], enc_f32(m.z));
                atomicMax(&maxu[cur * 128 + f4 + 3], enc_f32(m.w));
            }
            s = make_float4(0.f, 0.f, 0.f, 0.f);
            m = make_float4(-INFINITY, -INFINITY, -INFINITY, -INFINITY);
            cur = b;
        }
        s.x += v.x; s.y += v.y; s.z += v.z; s.w += v.w;
        m.x = fmaxf(m.x, v.x); m.y = fmaxf(m.y, v.y);
        m.z = fmaxf(m.z, v.z); m.w = fmaxf(m.w, v.w);
    }
    if (cur >= 0) {
        atomicAdd(&sums[cur * 128 + f4 + 0], s.x);
        atomicAdd(&sums[cur * 128 + f4 + 1], s.y);
        atomicAdd(&sums[cur * 128 + f4 + 2], s.z);
        atomicAdd(&sums[cur * 128 + f4 + 3], s.w);
        atomicMax(&maxu[cur * 128 + f4 + 0], enc_f32(m.x));
        atomicMax(&maxu[cur * 128 + f4 + 1], enc_f32(m.y));
        atomicMax(&maxu[cur * 128 + f4 + 2], enc_f32(m.z));
        atomicMax(&maxu[cur * 128 + f4 + 3], enc_f32(m.w));
    }
}

// ---------------------------------------------------------------------------
// Pool stage 2: finalize [sum | max | mean] per graph
// ---------------------------------------------------------------------------
__global__ __launch_bounds__(128) void pool_final_k(
    const float* __restrict__ sums, const unsigned* __restrict__ maxu,
    const int* __restrict__ goffs, float* __restrict__ gout)
{
    const int g = blockIdx.x, f = threadIdx.x;
    const int cnt = goffs[g + 1] - goffs[g];
    const float s = sums[g * 128 + f];
    float mx = (cnt > 0) ? dec_f32(maxu[g * 128 + f]) : 0.0f;
    if (!isfinite(mx)) mx = 0.0f;
    const float mean = s / fmaxf((float)cnt, 1.0f);
    gout[g * 384 + f]       = s;
    gout[g * 384 + 128 + f] = mx;
    gout[g * 384 + 256 + f] = mean;
}

// ---------------------------------------------------------------------------
// MLP head: one block per graph
// ---------------------------------------------------------------------------
__global__ __launch_bounds__(192) void mlp_k(const float* __restrict__ gbuf,
                                             const float* __restrict__ W1,
                                             const float* __restrict__ b1,
                                             const float* __restrict__ W2,
                                             const float* __restrict__ b2,
                                             float* __restrict__ out)
{
    __shared__ float gr[384];
    __shared__ float g1[192];
    const int g = blockIdx.x, t = threadIdx.x;
    for (int i = t; i < 384; i += 192) gr[i] = gbuf[g * 384 + i];
    __syncthreads();
    float acc = b1[t];
    for (int k = 0; k < 384; k++) acc += gr[k] * W1[k * 192 + t];
    acc = acc > 0.f ? acc : 0.01f * acc;
    g1[t] = acc;
    __syncthreads();
    if (t < 10) {
        float a = b2[t];
        for (int k = 0; k < 192; k++) a += g1[k] * W2[k * 10 + t];
        a = a > 0.f ? a : 0.01f * a;
        out[g * 10 + t] = a;
    }
}

// ---------------------------------------------------------------------------
extern "C" void kernel_launch(void* const* d_in, const int* in_sizes, int n_in,
                              void* d_out, int out_size, void* d_ws, size_t ws_size,
                              hipStream_t stream)
{
    const float* x      = (const float*)d_in[0];
    const int*   ei     = (const int*)d_in[1];
    const int*   batch  = (const int*)d_in[2];
    const float* W_emb  = (const float*)d_in[3];
    const float* b_emb  = (const float*)d_in[4];
    const float* W_conv = (const float*)d_in[5];
    const float* b_conv = (const float*)d_in[6];
    const float* W1     = (const float*)d_in[7];
    const float* b1     = (const float*)d_in[8];
    const float* W2     = (const float*)d_in[9];
    const float* b2     = (const float*)d_in[10];
    float* out = (float*)d_out;

    const int N  = in_sizes[2];          // 100000
    const int E  = in_sizes[1] / 2;      // 1600000
    const int G  = 128;
    const int NL = 5;
    const int HID = 128;

    const int* e_src = ei;
    const int* e_dst = ei + E;

    // workspace carve-up
    char* ws = (char*)d_ws;
    size_t off = 0;
    auto alloc = [&](size_t bytes) -> void* {
        void* p = ws + off;
        off += (bytes + 255) & ~(size_t)255;
        return p;
    };
    float*    hbuf     = (float*)   alloc((size_t)N * HID * 4);
    float*    hwbuf    = (float*)   alloc((size_t)N * HID * 4);
    float*    dinv     = (float*)   alloc((size_t)N * 4);
    int*      cnt      = (int*)     alloc((size_t)N * 4);
    int*      offs     = (int*)     alloc((size_t)(N + 1) * 4);
    int*      bsums    = (int*)     alloc(512 * 4);
    int*      csr_src  = (int*)     alloc((size_t)E * 4);
    float*    csr_norm = (float*)   alloc((size_t)E * 4);
    int*      goffs    = (int*)     alloc((size_t)(G + 1) * 4);
    float*    gbuf     = (float*)   alloc((size_t)G * 384 * 4);
    float*    psums    = (float*)   alloc((size_t)G * 128 * 4);
    unsigned* pmaxu    = (unsigned*)alloc((size_t)G * 128 * 4);

    const int nb_nodes = (N + 255) / 256;
    const int nb_edges = (E + 255) / 256;

    // 1) degree + dinv
    hipMemsetAsync(cnt, 0, (size_t)N * 4, stream);
    count_edges_k<<<nb_edges, 256, 0, stream>>>(e_dst, cnt, E);
    dinv_k<<<nb_nodes, 256, 0, stream>>>(cnt, dinv, N);

    // 2) CSR offsets (exclusive scan of cnt)
    scan_block_k<<<nb_nodes, 256, 0, stream>>>(cnt, offs, bsums, N);
    scan_tops_k<<<1, 512, 0, stream>>>(bsums, nb_nodes);
    scan_add_k<<<nb_nodes, 256, 0, stream>>>(offs, bsums, N, E);

    // 3) CSR fill
    hipMemsetAsync(cnt, 0, (size_t)N * 4, stream);
    fill_csr_k<<<nb_edges, 256, 0, stream>>>(e_src, e_dst, offs, cnt, dinv,
                                             csr_src, csr_norm, E);

    // 4) input embedding: h = x @ W_emb + b_emb
    dense_k<64, true><<<(N + 63) / 64, 256, 0, stream>>>(x, W_emb, b_emb, hbuf, N);

    // 5) GCN layers
    for (int l = 0; l < NL; l++) {
        dense_k<128, false><<<(N + 63) / 64, 256, 0, stream>>>(
            hbuf, W_conv + (size_t)l * HID * HID, nullptr, hwbuf, N);
        aggregate_k<<<(N + 3) / 4, 256, 0, stream>>>(
            hwbuf, offs, csr_src, csr_norm, dinv, b_conv + (size_t)l * HID, hbuf, N);
    }

    // 6) pooling (parallel two-stage)
    graph_bounds_k<<<nb_nodes, 256, 0, stream>>>(batch, goffs, N, G);
    hipMemsetAsync(psums, 0, (size_t)G * 128 * 4, stream);
    hipMemsetAsync(pmaxu, 0, (size_t)G * 128 * 4, stream);
    pool_partial_k<<<(N + POOL_CHUNK - 1) / POOL_CHUNK, 128, 0, stream>>>(
        hbuf, batch, psums, pmaxu, N);
    pool_final_k<<<G, 128, 0, stream>>>(psums, pmaxu, goffs, gbuf);

    // 7) MLP head
    mlp_k<<<G, 192, 0, stream>>>(gbuf, W1, b1, W2, b2, out);
}

// Round 3
// 1266.569 us; speedup vs baseline: 1.3217x; 1.1897x over previous
//
#include <hip/hip_runtime.h>
#include <math.h>

// ---------------------------------------------------------------------------
// Dense: out[M,128] = A[M,K] @ W[K,128] (+ bias). W staged in LDS.
// block = 256 threads; each block does 64 rows; micro-tile 8 rows x 4 cols.
// ---------------------------------------------------------------------------
template<int K, bool HAS_BIAS>
__global__ __launch_bounds__(256) void dense_k(
    const float* __restrict__ A, const float* __restrict__ W,
    const float* __restrict__ bias, float* __restrict__ out, int M)
{
    __shared__ float Wl[K * 128];
    const int t = threadIdx.x;
    for (int idx = t * 4; idx < K * 128; idx += 1024)
        *(float4*)&Wl[idx] = *(const float4*)&W[idx];
    __syncthreads();

    const int tx = t & 31, ty = t >> 5;
    const int c0 = tx * 4;
    const long row0 = (long)blockIdx.x * 64 + (long)ty * 8;

    const float* Ap[8];
#pragma unroll
    for (int i = 0; i < 8; i++) {
        long r = row0 + i; if (r > (long)M - 1) r = (long)M - 1;
        Ap[i] = A + r * K;
    }
    float4 acc[8];
#pragma unroll
    for (int i = 0; i < 8; i++) acc[i] = make_float4(0.f, 0.f, 0.f, 0.f);

    for (int k = 0; k < K; k += 4) {
        const float4 w0 = *(const float4*)&Wl[(k + 0) * 128 + c0];
        const float4 w1 = *(const float4*)&Wl[(k + 1) * 128 + c0];
        const float4 w2 = *(const float4*)&Wl[(k + 2) * 128 + c0];
        const float4 w3 = *(const float4*)&Wl[(k + 3) * 128 + c0];
#pragma unroll
        for (int i = 0; i < 8; i++) {
            const float4 a = *(const float4*)(Ap[i] + k);
            acc[i].x += a.x * w0.x + a.y * w1.x + a.z * w2.x + a.w * w3.x;
            acc[i].y += a.x * w0.y + a.y * w1.y + a.z * w2.y + a.w * w3.y;
            acc[i].z += a.x * w0.z + a.y * w1.z + a.z * w2.z + a.w * w3.z;
            acc[i].w += a.x * w0.w + a.y * w1.w + a.z * w2.w + a.w * w3.w;
        }
    }
    float4 bv = make_float4(0.f, 0.f, 0.f, 0.f);
    if (HAS_BIAS) bv = *(const float4*)&bias[c0];
#pragma unroll
    for (int i = 0; i < 8; i++) {
        long r = row0 + i;
        if (r < M) {
            float4 o;
            o.x = acc[i].x + bv.x; o.y = acc[i].y + bv.y;
            o.z = acc[i].z + bv.z; o.w = acc[i].w + bv.w;
            *(float4*)&out[r * 128 + c0] = o;
        }
    }
}

// ---------------------------------------------------------------------------
// Degree count (real edges only; self-loop added analytically later)
// ---------------------------------------------------------------------------
__global__ void count_edges_k(const int* __restrict__ dst, int* __restrict__ cnt, int E)
{
    int e = blockIdx.x * 256 + threadIdx.x;
    if (e < E) atomicAdd(&cnt[dst[e]], 1);
}

__global__ void dinv_k(const int* __restrict__ cnt, float* __restrict__ dinv, int N)
{
    int i = blockIdx.x * 256 + threadIdx.x;
    if (i < N) dinv[i] = rsqrtf((float)cnt[i] + 1.0f);   // +1 = self loop
}

// ---------------------------------------------------------------------------
// 3-kernel exclusive prefix scan over cnt -> offs
// ---------------------------------------------------------------------------
__global__ void scan_block_k(const int* __restrict__ cnt, int* __restrict__ offs,
                             int* __restrict__ bsums, int N)
{
    __shared__ int tmp[256];
    int i = blockIdx.x * 256 + threadIdx.x;
    int v = (i < N) ? cnt[i] : 0;
    tmp[threadIdx.x] = v;
    __syncthreads();
    for (int off = 1; off < 256; off <<= 1) {
        int add = (threadIdx.x >= off) ? tmp[threadIdx.x - off] : 0;
        __syncthreads();
        tmp[threadIdx.x] += add;
        __syncthreads();
    }
    if (i < N) offs[i] = tmp[threadIdx.x] - v;           // exclusive within block
    if (threadIdx.x == 255) bsums[blockIdx.x] = tmp[255];
}

__global__ void scan_tops_k(int* __restrict__ bsums, int nb)
{
    __shared__ int tmp[512];
    int t = threadIdx.x;
    int v = (t < nb) ? bsums[t] : 0;
    tmp[t] = v;
    __syncthreads();
    for (int off = 1; off < 512; off <<= 1) {
        int add = (t >= off) ? tmp[t - off] : 0;
        __syncthreads();
        tmp[t] += add;
        __syncthreads();
    }
    if (t < nb) bsums[t] = tmp[t] - v;                   // exclusive over blocks
}

__global__ void scan_add_k(int* __restrict__ offs, const int* __restrict__ bsums,
                           int N, int E)
{
    int i = blockIdx.x * 256 + threadIdx.x;
    if (i < N) offs[i] += bsums[blockIdx.x];
    if (i == 0) offs[N] = E;
}

// ---------------------------------------------------------------------------
// CSR fill: interleaved (src, norm) pairs grouped by dst
// ---------------------------------------------------------------------------
__global__ void fill_csr_k(const int* __restrict__ src, const int* __restrict__ dst,
                           const int* __restrict__ offs, int* __restrict__ fillc,
                           const float* __restrict__ dinv,
                           int2* __restrict__ csr, int E)
{
    int e = blockIdx.x * 256 + threadIdx.x;
    if (e >= E) return;
    int s = src[e], d = dst[e];
    int slot = offs[d] + atomicAdd(&fillc[d], 1);
    int2 p;
    p.x = s;
    p.y = __float_as_int(dinv[s] * dinv[d]);
    csr[slot] = p;
}

// ---------------------------------------------------------------------------
// Aggregation: one wave per node, lane handles 2 features (float2).
// Edge loop unrolled x4 -> 4 independent 512B gathers in flight per wave.
// ---------------------------------------------------------------------------
__global__ __launch_bounds__(256) void aggregate_k(
    const float* __restrict__ hw, const int* __restrict__ offs,
    const int2* __restrict__ csr, const float* __restrict__ dinv,
    const float* __restrict__ bconv, float* __restrict__ hout, int N)
{
    const int wid = threadIdx.x >> 6;
    const int lane = threadIdx.x & 63;
    const long node = (long)blockIdx.x * 4 + wid;
    if (node >= N) return;
    const int f = lane * 2;

    const float di = dinv[node];
    float2 self = *(const float2*)&hw[node * 128 + f];
    float2 acc;
    acc.x = self.x * di * di;
    acc.y = self.y * di * di;

    int k = offs[node];
    const int end = offs[node + 1];

    while (k + 4 <= end) {
        const int2 e0 = csr[k + 0];
        const int2 e1 = csr[k + 1];
        const int2 e2 = csr[k + 2];
        const int2 e3 = csr[k + 3];
        const float2 v0 = *(const float2*)&hw[(long)e0.x * 128 + f];
        const float2 v1 = *(const float2*)&hw[(long)e1.x * 128 + f];
        const float2 v2 = *(const float2*)&hw[(long)e2.x * 128 + f];
        const float2 v3 = *(const float2*)&hw[(long)e3.x * 128 + f];
        const float w0 = __int_as_float(e0.y);
        const float w1 = __int_as_float(e1.y);
        const float w2 = __int_as_float(e2.y);
        const float w3 = __int_as_float(e3.y);
        acc.x += v0.x * w0 + v1.x * w1 + v2.x * w2 + v3.x * w3;
        acc.y += v0.y * w0 + v1.y * w1 + v2.y * w2 + v3.y * w3;
        k += 4;
    }
    while (k < end) {
        const int2 e = csr[k++];
        const float w = __int_as_float(e.y);
        const float2 v = *(const float2*)&hw[(long)e.x * 128 + f];
        acc.x += v.x * w;
        acc.y += v.y * w;
    }

    const float2 b = *(const float2*)&bconv[f];
    float2 o;
    o.x = tanhf(acc.x + b.x);
    o.y = tanhf(acc.y + b.y);
    *(float2*)&hout[node * 128 + f] = o;
}

// ---------------------------------------------------------------------------
// Graph ranges from sorted batch
// ---------------------------------------------------------------------------
__global__ void graph_bounds_k(const int* __restrict__ batch, int* __restrict__ goffs,
                               int N, int G)
{
    int i = blockIdx.x * 256 + threadIdx.x;
    if (i >= N) return;
    int b = batch[i];
    int prev = (i == 0) ? -1 : batch[i - 1];
    for (int g = prev + 1; g <= b; g++) goffs[g] = i;
    if (i == N - 1)
        for (int g = b + 1; g <= G; g++) goffs[g] = N;
}

// ---------------------------------------------------------------------------
// Pool stage 1: parallel partial reduction over node chunks.
// ---------------------------------------------------------------------------
__device__ __forceinline__ unsigned enc_f32(float x)
{
    unsigned u = __float_as_uint(x);
    return (u & 0x80000000u) ? ~u : (u | 0x80000000u);
}
__device__ __forceinline__ float dec_f32(unsigned u)
{
    return (u & 0x80000000u) ? __uint_as_float(u ^ 0x80000000u)
                             : __uint_as_float(~u);
}

#define POOL_CHUNK 32

__global__ __launch_bounds__(128) void pool_partial_k(
    const float* __restrict__ h, const int* __restrict__ batch,
    float* __restrict__ sums, unsigned* __restrict__ maxu, int N)
{
    const int t = threadIdx.x;
    const int lane = t & 31;          // feature group: 4 floats
    const int sub = t >> 5;           // row offset within 4-row sweep
    const int f4 = lane * 4;
    const int i0 = blockIdx.x * POOL_CHUNK;
    const int i1 = min(i0 + POOL_CHUNK, N);

    int cur = -1;
    float4 s = make_float4(0.f, 0.f, 0.f, 0.f);
    float4 m = make_float4(-INFINITY, -INFINITY, -INFINITY, -INFINITY);

#pragma unroll 4
    for (int i = i0 + sub; i < i1; i += 4) {
        const int b = batch[i];
        const float4 v = *(const float4*)&h[(long)i * 128 + f4];
        if (b != cur) {
            if (cur >= 0) {
                atomicAdd(&sums[cur * 128 + f4 + 0], s.x);
                atomicAdd(&sums[cur * 128 + f4 + 1], s.y);
                atomicAdd(&sums[cur * 128 + f4 + 2], s.z);
                atomicAdd(&sums[cur * 128 + f4 + 3], s.w);
                atomicMax(&maxu[cur * 128 + f4 + 0], enc_f32(m.x));
                atomicMax(&maxu[cur * 128 + f4 + 1], enc_f32(m.y));
                atomicMax(&maxu[cur * 128 + f4 + 2], enc_f32(m.z));
                atomicMax(&maxu[cur * 128 + f4 + 3], enc_f32(m.w));
            }
            s = make_float4(0.f, 0.f, 0.f, 0.f);
            m = make_float4(-INFINITY, -INFINITY, -INFINITY, -INFINITY);
            cur = b;
        }
        s.x += v.x; s.y += v.y; s.z += v.z; s.w += v.w;
        m.x = fmaxf(m.x, v.x); m.y = fmaxf(m.y, v.y);
        m.z = fmaxf(m.z, v.z); m.w = fmaxf(m.w, v.w);
    }
    if (cur >= 0) {
        atomicAdd(&sums[cur * 128 + f4 + 0], s.x);
        atomicAdd(&sums[cur * 128 + f4 + 1], s.y);
        atomicAdd(&sums[cur * 128 + f4 + 2], s.z);
        atomicAdd(&sums[cur * 128 + f4 + 3], s.w);
        atomicMax(&maxu[cur * 128 + f4 + 0], enc_f32(m.x));
        atomicMax(&maxu[cur * 128 + f4 + 1], enc_f32(m.y));
        atomicMax(&maxu[cur * 128 + f4 + 2], enc_f32(m.z));
        atomicMax(&maxu[cur * 128 + f4 + 3], enc_f32(m.w));
    }
}

// ---------------------------------------------------------------------------
// Pool stage 2: finalize [sum | max | mean] per graph
// ---------------------------------------------------------------------------
__global__ __launch_bounds__(128) void pool_final_k(
    const float* __restrict__ sums, const unsigned* __restrict__ maxu,
    const int* __restrict__ goffs, float* __restrict__ gout)
{
    const int g = blockIdx.x, f = threadIdx.x;
    const int cnt = goffs[g + 1] - goffs[g];
    const float s = sums[g * 128 + f];
    float mx = (cnt > 0) ? dec_f32(maxu[g * 128 + f]) : 0.0f;
    if (!isfinite(mx)) mx = 0.0f;
    const float mean = s / fmaxf((float)cnt, 1.0f);
    gout[g * 384 + f]       = s;
    gout[g * 384 + 128 + f] = mx;
    gout[g * 384 + 256 + f] = mean;
}

// ---------------------------------------------------------------------------
// MLP head: one block per graph
// ---------------------------------------------------------------------------
__global__ __launch_bounds__(192) void mlp_k(const float* __restrict__ gbuf,
                                             const float* __restrict__ W1,
                                             const float* __restrict__ b1,
                                             const float* __restrict__ W2,
                                             const float* __restrict__ b2,
                                             float* __restrict__ out)
{
    __shared__ float gr[384];
    __shared__ float g1[192];
    const int g = blockIdx.x, t = threadIdx.x;
    for (int i = t; i < 384; i += 192) gr[i] = gbuf[g * 384 + i];
    __syncthreads();
    float acc = b1[t];
    for (int k = 0; k < 384; k++) acc += gr[k] * W1[k * 192 + t];
    acc = acc > 0.f ? acc : 0.01f * acc;
    g1[t] = acc;
    __syncthreads();
    if (t < 10) {
        float a = b2[t];
        for (int k = 0; k < 192; k++) a += g1[k] * W2[k * 10 + t];
        a = a > 0.f ? a : 0.01f * a;
        out[g * 10 + t] = a;
    }
}

// ---------------------------------------------------------------------------
extern "C" void kernel_launch(void* const* d_in, const int* in_sizes, int n_in,
                              void* d_out, int out_size, void* d_ws, size_t ws_size,
                              hipStream_t stream)
{
    const float* x      = (const float*)d_in[0];
    const int*   ei     = (const int*)d_in[1];
    const int*   batch  = (const int*)d_in[2];
    const float* W_emb  = (const float*)d_in[3];
    const float* b_emb  = (const float*)d_in[4];
    const float* W_conv = (const float*)d_in[5];
    const float* b_conv = (const float*)d_in[6];
    const float* W1     = (const float*)d_in[7];
    const float* b1     = (const float*)d_in[8];
    const float* W2     = (const float*)d_in[9];
    const float* b2     = (const float*)d_in[10];
    float* out = (float*)d_out;

    const int N  = in_sizes[2];          // 100000
    const int E  = in_sizes[1] / 2;      // 1600000
    const int G  = 128;
    const int NL = 5;
    const int HID = 128;

    const int* e_src = ei;
    const int* e_dst = ei + E;

    // workspace carve-up
    char* ws = (char*)d_ws;
    size_t off = 0;
    auto alloc = [&](size_t bytes) -> void* {
        void* p = ws + off;
        off += (bytes + 255) & ~(size_t)255;
        return p;
    };
    float*    hbuf     = (float*)   alloc((size_t)N * HID * 4);
    float*    hwbuf    = (float*)   alloc((size_t)N * HID * 4);
    float*    dinv     = (float*)   alloc((size_t)N * 4);
    int*      cnt      = (int*)     alloc((size_t)N * 4);
    int*      offs     = (int*)     alloc((size_t)(N + 1) * 4);
    int*      bsums    = (int*)     alloc(512 * 4);
    int2*     csr      = (int2*)    alloc((size_t)E * 8);
    int*      goffs    = (int*)     alloc((size_t)(G + 1) * 4);
    float*    gbuf     = (float*)   alloc((size_t)G * 384 * 4);
    float*    psums    = (float*)   alloc((size_t)G * 128 * 4);
    unsigned* pmaxu    = (unsigned*)alloc((size_t)G * 128 * 4);

    const int nb_nodes = (N + 255) / 256;
    const int nb_edges = (E + 255) / 256;

    // 1) degree + dinv
    hipMemsetAsync(cnt, 0, (size_t)N * 4, stream);
    count_edges_k<<<nb_edges, 256, 0, stream>>>(e_dst, cnt, E);
    dinv_k<<<nb_nodes, 256, 0, stream>>>(cnt, dinv, N);

    // 2) CSR offsets (exclusive scan of cnt)
    scan_block_k<<<nb_nodes, 256, 0, stream>>>(cnt, offs, bsums, N);
    scan_tops_k<<<1, 512, 0, stream>>>(bsums, nb_nodes);
    scan_add_k<<<nb_nodes, 256, 0, stream>>>(offs, bsums, N, E);

    // 3) CSR fill
    hipMemsetAsync(cnt, 0, (size_t)N * 4, stream);
    fill_csr_k<<<nb_edges, 256, 0, stream>>>(e_src, e_dst, offs, cnt, dinv, csr, E);

    // 4) input embedding: h = x @ W_emb + b_emb
    dense_k<64, true><<<(N + 63) / 64, 256, 0, stream>>>(x, W_emb, b_emb, hbuf, N);

    // 5) GCN layers
    for (int l = 0; l < NL; l++) {
        dense_k<128, false><<<(N + 63) / 64, 256, 0, stream>>>(
            hbuf, W_conv + (size_t)l * HID * HID, nullptr, hwbuf, N);
        aggregate_k<<<(N + 3) / 4, 256, 0, stream>>>(
            hwbuf, offs, csr, dinv, b_conv + (size_t)l * HID, hbuf, N);
    }

    // 6) pooling (parallel two-stage)
    graph_bounds_k<<<nb_nodes, 256, 0, stream>>>(batch, goffs, N, G);
    hipMemsetAsync(psums, 0, (size_t)G * 128 * 4, stream);
    hipMemsetAsync(pmaxu, 0, (size_t)G * 128 * 4, stream);
    pool_partial_k<<<(N + POOL_CHUNK - 1) / POOL_CHUNK, 128, 0, stream>>>(
        hbuf, batch, psums, pmaxu, N);
    pool_final_k<<<G, 128, 0, stream>>>(psums, pmaxu, goffs, gbuf);

    // 7) MLP head
    mlp_k<<<G, 192, 0, stream>>>(gbuf, W1, b1, W2, b2, out);
}